// Round 3
// baseline (366.525 us; speedup 1.0000x reference)
//
#include <hip/hip_runtime.h>

typedef unsigned short ushort_t;
typedef __attribute__((ext_vector_type(8))) short short8;
typedef __attribute__((ext_vector_type(8))) unsigned short ushort8;
typedef __attribute__((ext_vector_type(4))) unsigned short ushort4v;
typedef __attribute__((ext_vector_type(4))) float f32x4;
typedef __attribute__((ext_vector_type(4))) float float4v;

__device__ __forceinline__ float bf2f(ushort_t u) {
  return __uint_as_float(((unsigned)u) << 16);
}
__device__ __forceinline__ ushort_t f2bf(float f) {
  unsigned u = __float_as_uint(f);
  u += 0x7fffu + ((u >> 16) & 1u);   // RNE; inputs never NaN
  return (ushort_t)(u >> 16);
}

// async global->LDS, 16B per lane. LDS dest is wave-uniform base + lane*16.
__device__ __forceinline__ void gload16(ushort_t* lds, const ushort_t* g) {
  __builtin_amdgcn_global_load_lds(
      (const __attribute__((address_space(1))) unsigned int*)g,
      (__attribute__((address_space(3))) unsigned int*)lds, 16, 0, 0);
}

// ---------------- alpha = mean(|w|) + 1e-8 (two-stage, deterministic) ----------------
__global__ void k_abs_partial(const float* __restrict__ w1, const float* __restrict__ w2,
                              const float* __restrict__ w3, const float* __restrict__ w4,
                              float* __restrict__ apart) {
  int wy = blockIdx.y;
  const float* w; int n;
  if (wy == 0)      { w = w1; n = 1024 * 784; }
  else if (wy == 1) { w = w2; n = 512 * 1024; }
  else if (wy == 2) { w = w3; n = 256 * 512; }
  else              { w = w4; n = 10 * 256; }
  float s = 0.f;
  for (int i = blockIdx.x * 256 + threadIdx.x; i < n; i += 64 * 256)
    s += fabsf(w[i]);
  __shared__ float red[256];
  red[threadIdx.x] = s;
  __syncthreads();
  for (int st = 128; st > 0; st >>= 1) {
    if (threadIdx.x < st) red[threadIdx.x] += red[threadIdx.x + st];
    __syncthreads();
  }
  if (threadIdx.x == 0) apart[wy * 64 + blockIdx.x] = red[0];
}

__global__ void k_alpha_fin(const float* __restrict__ apart, float* __restrict__ alphas) {
  int wid = threadIdx.x >> 6, lane = threadIdx.x & 63;
  float v = apart[wid * 64 + lane];
  #pragma unroll
  for (int off = 32; off > 0; off >>= 1) v += __shfl_xor(v, off);
  if (lane == 0) {
    float inv;
    if (wid == 0)      inv = 1.f / (1024.f * 784.f);
    else if (wid == 1) inv = 1.f / (512.f * 1024.f);
    else if (wid == 2) inv = 1.f / (256.f * 512.f);
    else               inv = 1.f / 2560.f;
    alphas[wid] = v * inv + 1e-8f;
  }
}

// ---------------- ternary quantize -> bf16 {-1,0,1}, alpha factored out ----------------
__global__ void k_quantize(const float* __restrict__ w1, const float* __restrict__ w2,
                           const float* __restrict__ w3, const float* __restrict__ w4,
                           ushort_t* __restrict__ q1, ushort_t* __restrict__ q2,
                           ushort_t* __restrict__ q3, ushort_t* __restrict__ q4,
                           const float* __restrict__ alphas) {
  int wy = blockIdx.y;
  const float* w; ushort_t* q; int R, K, Kp;
  if (wy == 0)      { w = w1; q = q1; R = 1024; K = 784;  Kp = 832;  }
  else if (wy == 1) { w = w2; q = q2; R = 512;  K = 1024; Kp = 1024; }
  else if (wy == 2) { w = w3; q = q3; R = 256;  K = 512;  Kp = 512;  }
  else              { w = w4; q = q4; R = 10;   K = 256;  Kp = 256;  }
  float a = alphas[wy];
  int total = R * Kp;
  for (int i = blockIdx.x * 256 + threadIdx.x; i < total; i += gridDim.x * 256) {
    int r = i / Kp, k = i - r * Kp;
    float v = 0.f;
    if (k < K) {
      float t = rintf(w[r * K + k] / a);   // rintf = RNE, matches jnp.round
      v = fminf(1.f, fmaxf(-1.f, t));
    }
    q[i] = f2bf(v);   // exact for {-1,0,1}
  }
}

// ---------------- fused 128x128-tile bf16 MFMA GEMM ----------------
// C_bf16 = alpha * (pre(A) @ B^T), plus per-column partial sums/sum-sq of the
// STORED bf16 C (BN batch stats) into psum/psq[rowt*2+wr][col].
// MODE 0: A is f32 (the network input x), pre() = bf16 convert + zero-pad K.
// MODE 1: A is bf16 raw pre-BN activations; pre() = relu(A*S + B) with S,B =
//         previous layer's folded BN scale/shift (SB_in), then bf16.
// A-path is reg-staged (T14 issue-early/write-late) so pre() can be applied;
// B-path stays global_load_lds width=16. 1D grid + bijective XCD swizzle.
template <int MODE>
__global__ __launch_bounds__(256, MODE == 0 ? 2 : 3) void k_gemm_fused(
    const void* __restrict__ Avoid, const ushort_t* __restrict__ Bw,
    ushort_t* __restrict__ C, const float* __restrict__ alphas, int layer,
    const float* __restrict__ SB_in,
    float* __restrict__ psum, float* __restrict__ psq,
    int N, int Kp, int Astride, int nbxl) {
  __shared__ ushort_t As[8192];   // [128][64] linear
  __shared__ ushort_t Bs[8192];
  const int tid = threadIdx.x;
  const int lane = tid & 63;
  const int wv = tid >> 6;
  const int wr = (tid >> 7) & 1;
  const int wc = (tid >> 6) & 1;
  const int l15 = lane & 15, l4 = lane >> 4;

  const int cpx = gridDim.x >> 3;                         // chunk per XCD
  const int orig = (blockIdx.x & 7) * cpx + (blockIdx.x >> 3);
  const int colt = orig & ((1 << nbxl) - 1);
  const int rowt = orig >> nbxl;                          // consecutive origs share rowt
  const int row0 = rowt << 7, col0 = colt << 7;

  f32x4 acc[4][4];
  #pragma unroll
  for (int m = 0; m < 4; ++m)
    #pragma unroll
    for (int n = 0; n < 4; ++n) acc[m][n] = (f32x4){0.f, 0.f, 0.f, 0.f};

  // B staging (gload_lds): wave wv owns rows [wv*32, wv*32+32)
  const int bsrow = lane >> 3;           // 0..7
  const int bsk = (lane & 7) << 3;       // 0..56
  const ushort_t* Bg = Bw + (size_t)(col0 + wv * 32 + bsrow) * Kp + bsk;
  ushort_t* Bsw = Bs + wv * 32 * 64;
  const size_t r8 = (size_t)8 * Kp;

  // A reg staging: thread covers rows srow + c*32, cols sk..sk+7 of the tile
  const int srow = tid >> 3;             // 0..31
  const int sk = (tid & 7) << 3;         // 0..56
  const int swoff = srow * 64 + sk;
  const float*    Xg = (const float*)Avoid    + (size_t)(row0 + srow) * Astride + sk;
  const ushort_t* Yg = (const ushort_t*)Avoid + (size_t)(row0 + srow) * Astride + sk;

  float4v  xr[4][2];   // MODE 0 raw f32
  ushort8  ua[4];      // MODE 1 raw bf16
  float4v  vS[2], vB[2];
  ushort8  wa[4];      // transformed bf16, ready for ds_write

  auto fetchA = [&](int kt) {
    if constexpr (MODE == 0) {
      const bool ok = (kt * 64 + sk) < 784;
      if (ok) {
        #pragma unroll
        for (int c = 0; c < 4; ++c) {
          const float* p = Xg + (size_t)c * 32 * 784 + kt * 64;
          xr[c][0] = *(const float4v*)p;
          xr[c][1] = *(const float4v*)(p + 4);
        }
      }
    } else {
      #pragma unroll
      for (int c = 0; c < 4; ++c)
        ua[c] = *(const ushort8*)(Yg + (size_t)c * 32 * Kp + kt * 64);
      const float* Sp = SB_in + kt * 64 + sk;
      const float* Bp = SB_in + Kp + kt * 64 + sk;
      vS[0] = *(const float4v*)Sp; vS[1] = *(const float4v*)(Sp + 4);
      vB[0] = *(const float4v*)Bp; vB[1] = *(const float4v*)(Bp + 4);
    }
  };
  auto transformA = [&](int kt) {
    if constexpr (MODE == 0) {
      const bool ok = (kt * 64 + sk) < 784;
      #pragma unroll
      for (int c = 0; c < 4; ++c)
        #pragma unroll
        for (int h = 0; h < 2; ++h)
          #pragma unroll
          for (int j = 0; j < 4; ++j)
            wa[c][h * 4 + j] = ok ? f2bf(xr[c][h][j]) : (ushort_t)0;
    } else {
      #pragma unroll
      for (int c = 0; c < 4; ++c)
        #pragma unroll
        for (int h = 0; h < 2; ++h)
          #pragma unroll
          for (int j = 0; j < 4; ++j) {
            float f = bf2f(ua[c][h * 4 + j]);
            float hv = fmaxf(f * vS[h][j] + vB[h][j], 0.f);
            wa[c][h * 4 + j] = f2bf(hv);
          }
    }
  };

  fetchA(0);
  transformA(0);

  const int nk = Kp >> 6;
  for (int kt = 0; kt < nk; ++kt) {
    __syncthreads();                     // previous compute done with LDS
    #pragma unroll
    for (int c = 0; c < 4; ++c)
      *(ushort8*)(As + swoff + c * 2048) = wa[c];
    const ushort_t* Bgk = Bg + (size_t)kt * 64;
    #pragma unroll
    for (int c = 0; c < 4; ++c) gload16(Bsw + c * 512, Bgk + c * r8);
    __syncthreads();                     // drains ds_write + gload_lds
    if (kt + 1 < nk) fetchA(kt + 1);     // issue next A loads under MFMA
    #pragma unroll
    for (int ks = 0; ks < 2; ++ks) {
      short8 af[4], bfv[4];
      #pragma unroll
      for (int m = 0; m < 4; ++m)
        af[m] = *(const short8*)(As + (wr * 64 + m * 16 + l15) * 64 + ks * 32 + l4 * 8);
      #pragma unroll
      for (int n = 0; n < 4; ++n)
        bfv[n] = *(const short8*)(Bs + (wc * 64 + n * 16 + l15) * 64 + ks * 32 + l4 * 8);
      #pragma unroll
      for (int m = 0; m < 4; ++m)
        #pragma unroll
        for (int n = 0; n < 4; ++n)
          acc[m][n] = __builtin_amdgcn_mfma_f32_16x16x32_bf16(af[m], bfv[n], acc[m][n], 0, 0, 0);
    }
    if (kt + 1 < nk) transformA(kt + 1);
  }

  // epilogue: store bf16 C and per-column partial stats of the stored values
  const float alpha = alphas[layer];
  float csum[4], csq[4];
  #pragma unroll
  for (int n = 0; n < 4; ++n) { csum[n] = 0.f; csq[n] = 0.f; }
  #pragma unroll
  for (int m = 0; m < 4; ++m) {
    const int rbase = row0 + wr * 64 + m * 16 + l4 * 4;
    #pragma unroll
    for (int n = 0; n < 4; ++n) {
      const int col = col0 + wc * 64 + n * 16 + l15;
      #pragma unroll
      for (int r = 0; r < 4; ++r) {
        ushort_t ub = f2bf(acc[m][n][r] * alpha);
        C[(size_t)(rbase + r) * N + col] = ub;
        float vv = bf2f(ub);
        csum[n] += vv;
        csq[n] += vv * vv;
      }
    }
  }
  #pragma unroll
  for (int n = 0; n < 4; ++n) {          // reduce over the 4 l4 groups (16 rows each)
    csum[n] += __shfl_xor(csum[n], 16);
    csum[n] += __shfl_xor(csum[n], 32);
    csq[n]  += __shfl_xor(csq[n], 16);
    csq[n]  += __shfl_xor(csq[n], 32);
  }
  if (l4 == 0) {
    const int prow = rowt * 2 + wr;      // 512 partial rows total
    #pragma unroll
    for (int n = 0; n < 4; ++n) {
      const int col = col0 + wc * 64 + n * 16 + l15;
      psum[(size_t)prow * N + col] = csum[n];
      psq [(size_t)prow * N + col] = csq[n];
    }
  }
}

// ---------------- fold BN: S = g/sqrt(var+eps), B = b - mean*S ----------------
__global__ void k_bn_fin(const float* __restrict__ psum, const float* __restrict__ psq,
                         const float* __restrict__ g, const float* __restrict__ bb,
                         int N, float* __restrict__ SB) {
  int f = blockIdx.x * 256 + threadIdx.x;
  float s = 0.f, q = 0.f;
  for (int i = 0; i < 512; ++i) {
    s += psum[(size_t)i * N + f];
    q += psq [(size_t)i * N + f];
  }
  float mean = s * (1.f / 32768.f);
  float var  = q * (1.f / 32768.f) - mean * mean;   // biased, matches torch/jnp
  float Sv = g[f] / sqrtf(var + 1e-5f);
  float Bv = bb[f] - mean * Sv;
  SB[f] = Sv;
  SB[N + f] = Bv;
}

// -------- final layer: out = alpha4 * (relu(bn3(y3)) @ t4^T); norm3 fused in --------
__global__ void k_final(const ushort_t* __restrict__ H, const ushort_t* __restrict__ W4,
                        const float* __restrict__ alphas, const float* __restrict__ SB,
                        float* __restrict__ out) {
  int lane = threadIdx.x & 63, wid = threadIdx.x >> 6;
  int row = blockIdx.x * 4 + wid;
  float a4 = alphas[3];
  ushort4v hv = *(const ushort4v*)(H + (size_t)row * 256 + lane * 4);
  float4v S = *(const float4v*)(SB + lane * 4);
  float4v Bv = *(const float4v*)(SB + 256 + lane * 4);
  float hf[4];
  #pragma unroll
  for (int j = 0; j < 4; ++j)
    hf[j] = fmaxf(bf2f(hv[j]) * S[j] + Bv[j], 0.f);   // BN3 + ReLU fused
  float acc[10];
  #pragma unroll
  for (int c = 0; c < 10; ++c) {
    ushort4v wv = *(const ushort4v*)(W4 + c * 256 + lane * 4);
    acc[c] = hf[0] * bf2f(wv[0]) + hf[1] * bf2f(wv[1]) +
             hf[2] * bf2f(wv[2]) + hf[3] * bf2f(wv[3]);
  }
  #pragma unroll
  for (int c = 0; c < 10; ++c) {
    #pragma unroll
    for (int off = 32; off > 0; off >>= 1) acc[c] += __shfl_xor(acc[c], off);
  }
  if (lane < 10) {
    float v = 0.f;
    #pragma unroll
    for (int c = 0; c < 10; ++c)
      if (lane == c) v = acc[c];
    out[(size_t)row * 10 + lane] = v * a4;
  }
}

// =====================================================================================
extern "C" void kernel_launch(void* const* d_in, const int* in_sizes, int n_in,
                              void* d_out, int out_size, void* d_ws, size_t ws_size,
                              hipStream_t stream) {
  const float* x  = (const float*)d_in[0];
  const float* w1 = (const float*)d_in[1];
  const float* w2 = (const float*)d_in[2];
  const float* w3 = (const float*)d_in[3];
  const float* w4 = (const float*)d_in[4];
  const float* g1 = (const float*)d_in[5];
  const float* b1 = (const float*)d_in[6];
  const float* g2 = (const float*)d_in[7];
  const float* b2 = (const float*)d_in[8];
  const float* g3 = (const float*)d_in[9];
  const float* b3 = (const float*)d_in[10];
  float* out = (float*)d_out;

  // workspace layout (~124.7 MB, all offsets 256B-aligned)
  char* ws = (char*)d_ws;
  float* alphas   = (float*)(ws + 0);
  float* apart    = (float*)(ws + 256);
  float* SB1      = (float*)(ws + 4096);                 // 2*1024 f32
  float* SB2      = (float*)(ws + 16384);                // 2*512 f32
  float* SB3      = (float*)(ws + 24576);                // 2*256 f32
  float* psum     = (float*)(ws + 32768);                // 512*1024 f32 (2 MB)
  float* psq      = (float*)(ws + 2129920);              // 2 MB
  ushort_t* wq1   = (ushort_t*)(ws + 4227072);           // 1024x832
  ushort_t* wq2   = (ushort_t*)(ws + 5931008);           // 512x1024
  ushort_t* wq3   = (ushort_t*)(ws + 6979584);           // 256x512
  ushort_t* wq4   = (ushort_t*)(ws + 7241728);           // 10x256
  ushort_t* y1    = (ushort_t*)(ws + 7246848);           // 32768x1024 raw (67 MB)
  ushort_t* y2    = (ushort_t*)(ws + 74355712);          // 32768x512 raw (33.5 MB)
  ushort_t* y3    = (ushort_t*)(ws + 107910144);         // 32768x256 raw (16.8 MB)

  dim3 blk(256);

  k_abs_partial<<<dim3(64, 4), blk, 0, stream>>>(w1, w2, w3, w4, apart);
  k_alpha_fin<<<1, blk, 0, stream>>>(apart, alphas);
  k_quantize<<<dim3(512, 4), blk, 0, stream>>>(w1, w2, w3, w4, wq1, wq2, wq3, wq4, alphas);

  // layer 1: A = x f32 (convert fused), 32768x1024, Kp=832, Astride=784
  k_gemm_fused<0><<<2048, blk, 0, stream>>>(x, wq1, y1, alphas, 0, nullptr,
                                            psum, psq, 1024, 832, 784, 3);
  k_bn_fin<<<4, blk, 0, stream>>>(psum, psq, g1, b1, 1024, SB1);

  // layer 2: A = y1 raw bf16 + BN1/ReLU fused in staging, 32768x512, K=1024
  k_gemm_fused<1><<<1024, blk, 0, stream>>>(y1, wq2, y2, alphas, 1, SB1,
                                            psum, psq, 512, 1024, 1024, 2);
  k_bn_fin<<<2, blk, 0, stream>>>(psum, psq, g2, b2, 512, SB2);

  // layer 3: A = y2 raw + BN2/ReLU fused, 32768x256, K=512
  k_gemm_fused<1><<<512, blk, 0, stream>>>(y2, wq3, y3, alphas, 2, SB2,
                                           psum, psq, 256, 512, 512, 1);
  k_bn_fin<<<1, blk, 0, stream>>>(psum, psq, g3, b3, 256, SB3);

  // layer 4: GEMV with BN3/ReLU fused
  k_final<<<8192, blk, 0, stream>>>(y3, wq4, alphas, SB3, out);
}